// Round 1
// baseline (46.860 us; speedup 1.0000x reference)
//
#include <hip/hip_runtime.h>

// out[row, j] for row in [0, 64*4096), j in [0,256):
//   j < 255 : sin(tau[row]*w[j] + b[j])
//   j == 255: tau[row]*w0 + b0
// 64 threads per row, 4 consecutive outputs per thread (float4 store).
// w/b fragments are row-invariant per thread -> hoisted to registers.

__global__ __launch_bounds__(256) void SineActivation_59742995087547_kernel(
    const float* __restrict__ tau,
    const float* __restrict__ w,
    const float* __restrict__ b,
    const float* __restrict__ w0,
    const float* __restrict__ b0,
    float* __restrict__ out,
    int n_rows)
{
    const int tid = threadIdx.x;
    const int j0 = (tid & 63) * 4;        // 64 threads cover 256 outputs
    const int row_in_blk = tid >> 6;      // 4 rows per 256-thread block

    const bool last = (j0 == 252);        // this thread's 4th elem is j=255
    float4 wv, bv;
    wv.x = w[j0 + 0]; bv.x = b[j0 + 0];
    wv.y = w[j0 + 1]; bv.y = b[j0 + 1];
    wv.z = w[j0 + 2]; bv.z = b[j0 + 2];
    if (last) { wv.w = w0[0];     bv.w = b0[0]; }
    else      { wv.w = w[j0 + 3]; bv.w = b[j0 + 3]; }

    const int row_stride = gridDim.x * 4;
    for (int row = blockIdx.x * 4 + row_in_blk; row < n_rows; row += row_stride) {
        const float t = tau[row];         // broadcast within 64-lane group
        float4 o;
        o.x = __sinf(fmaf(t, wv.x, bv.x));
        o.y = __sinf(fmaf(t, wv.y, bv.y));
        o.z = __sinf(fmaf(t, wv.z, bv.z));
        const float lin = fmaf(t, wv.w, bv.w);
        o.w = last ? lin : __sinf(lin);
        *reinterpret_cast<float4*>(out + (size_t)row * 256 + j0) = o;
    }
}

extern "C" void kernel_launch(void* const* d_in, const int* in_sizes, int n_in,
                              void* d_out, int out_size, void* d_ws, size_t ws_size,
                              hipStream_t stream) {
    const float* tau = (const float*)d_in[0];
    const float* w   = (const float*)d_in[1];
    const float* b   = (const float*)d_in[2];
    const float* w0  = (const float*)d_in[3];
    const float* b0  = (const float*)d_in[4];
    float* out = (float*)d_out;

    const int n_rows = in_sizes[0];       // 64*4096 = 262144 rows of 256
    const int grid = 2048;                // grid-stride, ~8 blocks/CU
    SineActivation_59742995087547_kernel<<<grid, 256, 0, stream>>>(
        tau, w, b, w0, b0, out, n_rows);
}